// Round 8
// baseline (527.673 us; speedup 1.0000x reference)
//
#include <hip/hip_runtime.h>
#include <hip/hip_bf16.h>
#include <stdint.h>

#define N_NODES 50000
#define N_PAD   50048   // 782 * 64
#define E_EDGES 800000
#define MT      391
#define MS64    782     // 64-row strips

typedef __bf16 bf16x8 __attribute__((ext_vector_type(8)));
typedef __bf16 bf16x4 __attribute__((ext_vector_type(4)));
typedef float  f32x4  __attribute__((ext_vector_type(4)));

// ---------------- CSR build ----------------
__global__ void count_deg(const int* __restrict__ ei, int* __restrict__ cnt) {
    int e = blockIdx.x * blockDim.x + threadIdx.x;
    if (e < E_EDGES) atomicAdd(&cnt[ei[E_EDGES + e]], 1);
}

#define SCAN_B 1024
__global__ void scan_block(const int* __restrict__ cnt, int* __restrict__ ptr,
                           int* __restrict__ bsum, int n) {
    __shared__ int buf[SCAN_B];
    int i = blockIdx.x * SCAN_B + threadIdx.x;
    int v = (i < n) ? cnt[i] : 0;
    buf[threadIdx.x] = v;
    __syncthreads();
    #pragma unroll
    for (int off = 1; off < SCAN_B; off <<= 1) {
        int t = (threadIdx.x >= (unsigned)off) ? buf[threadIdx.x - off] : 0;
        __syncthreads();
        buf[threadIdx.x] += t;
        __syncthreads();
    }
    if (i < n) ptr[i] = buf[threadIdx.x] - v;
    if (threadIdx.x == SCAN_B - 1) bsum[blockIdx.x] = buf[SCAN_B - 1];
}

__global__ void scan_bsums(int* __restrict__ bsum, int* __restrict__ boff, int nb,
                           int* __restrict__ total_out) {
    __shared__ int buf[64];
    int v = ((int)threadIdx.x < nb) ? bsum[threadIdx.x] : 0;
    buf[threadIdx.x] = v;
    __syncthreads();
    #pragma unroll
    for (int off = 1; off < 64; off <<= 1) {
        int t = (threadIdx.x >= (unsigned)off) ? buf[threadIdx.x - off] : 0;
        __syncthreads();
        buf[threadIdx.x] += t;
        __syncthreads();
    }
    if ((int)threadIdx.x < nb) boff[threadIdx.x] = buf[threadIdx.x] - v;
    if (threadIdx.x == 63) *total_out = buf[63];
}

__global__ void scan_add(int* __restrict__ ptr, const int* __restrict__ boff, int n) {
    int i = blockIdx.x * SCAN_B + threadIdx.x;
    if (i < n) ptr[i] += boff[blockIdx.x];
}

__global__ void fill_csr(const int* __restrict__ ei, const int* __restrict__ ptr,
                         int* __restrict__ cursor, int* __restrict__ col) {
    int e = blockIdx.x * blockDim.x + threadIdx.x;
    if (e < E_EDGES) {
        int dst = ei[E_EDGES + e];
        int pos = ptr[dst] + atomicAdd(&cursor[dst], 1);
        col[pos] = ei[e];
    }
}

// ---------------- one-shot fp32 -> bf16 conversion (x + all weights) -----------
#define XN      3200000
#define WTOT    983040
__global__ void cvt_all(const float* __restrict__ x,
                        const float* __restrict__ Ws1, const float* __restrict__ Ws2,
                        const float* __restrict__ Ws3, const float* __restrict__ Ws4,
                        const float* __restrict__ Wm1, const float* __restrict__ Wl1,
                        const float* __restrict__ Wm2, const float* __restrict__ Wl2,
                        __bf16* __restrict__ xb, __bf16* __restrict__ wbuf) {
    int i = blockIdx.x * blockDim.x + threadIdx.x;
    if (i < XN) { xb[i] = (__bf16)x[i]; return; }
    int j = i - XN;
    if (j >= WTOT) return;
    const float* s; int o;
    if      (j <  32768) { s = Ws1; o = j; }
    else if (j < 294912) { s = Ws2; o = j -  32768; }
    else if (j < 557056) { s = Ws3; o = j - 294912; }
    else if (j < 819200) { s = Ws4; o = j - 557056; }
    else if (j < 884736) { s = Wm1; o = j - 819200; }
    else if (j < 950272) { s = Wl1; o = j - 884736; }
    else if (j < 966656) { s = Wm2; o = j - 950272; }
    else                 { s = Wl2; o = j - 966656; }
    wbuf[j] = (__bf16)s[o];
}

// ---------------- aggregation (gather over CSR, fp32 accumulate) ---------------
__global__ void agg0_gather(const __bf16* __restrict__ xb, const int* __restrict__ ptr,
                            const int* __restrict__ col, __bf16* __restrict__ out) {
    int node = blockIdx.x * 4 + (threadIdx.x >> 6);
    int lane = threadIdx.x & 63;
    if (node >= N_PAD) return;
    long o = (long)node * 64 + lane;
    if (node >= N_NODES) { out[o] = (__bf16)0.0f; return; }
    float acc = (float)xb[o];
    int e0 = ptr[node], e1 = ptr[node + 1];
    int e = e0;
    for (; e + 8 <= e1; e += 8) {
        int c[8];
        #pragma unroll
        for (int u = 0; u < 8; ++u) c[u] = col[e + u];
        float v[8];
        #pragma unroll
        for (int u = 0; u < 8; ++u) v[u] = (float)xb[(long)c[u] * 64 + lane];
        #pragma unroll
        for (int u = 0; u < 8; ++u) acc += v[u];
    }
    for (; e < e1; ++e) acc += (float)xb[(long)col[e] * 64 + lane];
    out[o] = (__bf16)acc;
}

// unroll 8, low VGPR (28) -> occupancy 66%: TLP beats per-wave ILP (r6 lesson)
__global__ void aggt_gather(const __bf16* __restrict__ t, const int* __restrict__ ptr,
                            const int* __restrict__ col, const float* __restrict__ b_m1,
                            const float* __restrict__ b_l1, __bf16* __restrict__ p) {
    int node = blockIdx.x * 4 + (threadIdx.x >> 6);
    int lane = threadIdx.x & 63;
    if (node >= N_NODES) return;
    const int f0 = lane * 4;
    bf16x4 s = *(const bf16x4*)&t[(long)node * 256 + f0];
    float a0 = (float)s[0], a1 = (float)s[1], a2 = (float)s[2], a3 = (float)s[3];
    int e0 = ptr[node], e1 = ptr[node + 1];
    int e = e0;
    for (; e + 8 <= e1; e += 8) {
        int c[8];
        #pragma unroll
        for (int u = 0; u < 8; ++u) c[u] = col[e + u];
        bf16x4 v[8];
        #pragma unroll
        for (int u = 0; u < 8; ++u) v[u] = *(const bf16x4*)&t[(long)c[u] * 256 + f0];
        #pragma unroll
        for (int u = 0; u < 8; ++u) {
            a0 += (float)v[u][0]; a1 += (float)v[u][1];
            a2 += (float)v[u][2]; a3 += (float)v[u][3];
        }
    }
    for (; e < e1; ++e) {
        bf16x4 v = *(const bf16x4*)&t[(long)col[e] * 256 + f0];
        a0 += (float)v[0]; a1 += (float)v[1]; a2 += (float)v[2]; a3 += (float)v[3];
    }
    float b0, b1, b2, b3;
    if (f0 < 128) { b0 = b_m1[f0]; b1 = b_m1[f0+1]; b2 = b_m1[f0+2]; b3 = b_m1[f0+3]; }
    else          { b0 = b_l1[f0-128]; b1 = b_l1[f0-127]; b2 = b_l1[f0-126]; b3 = b_l1[f0-125]; }
    bf16x4 r;
    r[0] = (__bf16)fmaxf(a0 + b0, 0.0f);
    r[1] = (__bf16)fmaxf(a1 + b1, 0.0f);
    r[2] = (__bf16)fmaxf(a2 + b2, 0.0f);
    r[3] = (__bf16)fmaxf(a3 + b3, 0.0f);
    *(bf16x4*)&p[(long)node * 256 + f0] = r;
}

__device__ __forceinline__ void gl_lds16(const __bf16* g, __bf16* l) {
    __builtin_amdgcn_global_load_lds(
        (const __attribute__((address_space(1))) uint32_t*)g,
        (__attribute__((address_space(3))) uint32_t*)l, 16, 0, 0);
}

// ---------------- wide GEMM: block = 64-row strip x full N, col-loop inside ----
// C[M,N] = A[M,K]*W[N,K]^T (+bias, act), bf16 out. Block 256 thr, 4 waves,
// wave tile 64x64 (acc 4x4=64 VGPR). Block tile 64x256 per col-iter, NCT iters.
// A restaged per col-iter but L1/L2-hot -> beyond-L2 A-traffic 1x (the point).
// LDS 40 KB (A 8K + W 32K) -> 4 blocks/CU; staging BW-bound, implicit overlap.
// LDS swizzle: row r k-granule kt at slot kt^(r&7); 1-KB chunk = 8 rows.
template <int NCT, int ACT, bool BIAS>
__global__ __launch_bounds__(256) void gemm_wide(
    const __bf16* __restrict__ A, int lda, const __bf16* __restrict__ W,
    const float* __restrict__ bias, __bf16* __restrict__ C, int ldc, int K) {
    __shared__ __bf16 smem[20480];          // A 4096 | W 16384 elems (40 KB)
    __bf16* As = smem;
    __bf16* Ws = smem + 4096;

    const int tid  = threadIdx.x;
    const int wid  = tid >> 6;
    const int lane = tid & 63;
    const long row0 = (long)blockIdx.x * 64;

    const int srow = lane >> 3;             // row within 8-row chunk
    const int skg  = (lane & 7) ^ srow;     // k-granule for swizzled slot
    // A: 8 chunks; wave stages chunks 2w,2w+1
    const __bf16* gA[2]; __bf16* lA[2];
    #pragma unroll
    for (int i = 0; i < 2; ++i) {
        int c = wid * 2 + i;
        gA[i] = A + (row0 + c * 8 + srow) * (long)lda + skg * 8;
        lA[i] = As + c * 512;
    }
    // W: 32 chunks per col-tile; wave stages chunks 8w..8w+7
    __bf16* lW[8];
    long gWoff[8];
    #pragma unroll
    for (int j = 0; j < 8; ++j) {
        int c = wid * 8 + j;
        lW[j] = Ws + c * 512;
        gWoff[j] = (long)(c * 8 + srow) * K + skg * 8;   // row within 256-col tile
    }

    const int rA = lane & 15;
    const int q  = lane >> 4;
    const int r7 = rA & 7;
    const int ccol = lane & 15;
    const int crow = (lane >> 4) << 2;

    for (int ct = 0; ct < NCT; ++ct) {
        const __bf16* Wt = W + (long)ct * 256 * K;
        f32x4 acc[4][4];
        #pragma unroll
        for (int i = 0; i < 4; ++i)
            #pragma unroll
            for (int j = 0; j < 4; ++j) acc[i][j] = (f32x4)0.0f;

        for (int k0 = 0; k0 < K; k0 += 64) {
            #pragma unroll
            for (int i = 0; i < 2; ++i) gl_lds16(gA[i] + k0, lA[i]);
            #pragma unroll
            for (int j = 0; j < 8; ++j) gl_lds16(Wt + gWoff[j] + k0, lW[j]);
            __syncthreads();

            #pragma unroll
            for (int s = 0; s < 2; ++s) {
                const int slot = ((s * 4 + q) ^ r7) * 8;
                bf16x8 af[4], bf[4];
                #pragma unroll
                for (int mi = 0; mi < 4; ++mi)
                    af[mi] = *(const bf16x8*)&As[(mi * 16 + rA) * 64 + slot];
                #pragma unroll
                for (int ni = 0; ni < 4; ++ni)
                    bf[ni] = *(const bf16x8*)&Ws[(wid * 64 + ni * 16 + rA) * 64 + slot];
                #pragma unroll
                for (int mi = 0; mi < 4; ++mi)
                    #pragma unroll
                    for (int ni = 0; ni < 4; ++ni)
                        acc[mi][ni] = __builtin_amdgcn_mfma_f32_16x16x32_bf16(
                            af[mi], bf[ni], acc[mi][ni], 0, 0, 0);
            }
            __syncthreads();
        }

        // epilogue: C/D layout col=lane&15, row=(lane>>4)*4+reg. Stage 64x256
        // bf16 tile (32 KB) in dead staging LDS, then coalesced 16-B stores.
        #pragma unroll
        for (int mi = 0; mi < 4; ++mi) {
            #pragma unroll
            for (int ni = 0; ni < 4; ++ni) {
                int gc = wid * 64 + ni * 16 + ccol;
                float bv = BIAS ? bias[ct * 256 + gc] : 0.0f;
                #pragma unroll
                for (int r = 0; r < 4; ++r) {
                    float v = acc[mi][ni][r] + bv;
                    if (ACT == 1) v = (v > 0.0f) ? v : 0.1f * v;
                    else if (ACT == 2) v = fmaxf(v, 0.0f);
                    smem[(mi * 16 + crow + r) * 256 + gc] = (__bf16)v;
                }
            }
        }
        __syncthreads();
        #pragma unroll
        for (int i = 0; i < 8; ++i) {
            int o   = (i * 256 + tid) * 8;      // flat elem in 64x256
            int row = o >> 8;
            int co  = o & 255;
            *(bf16x8*)(C + (row0 + row) * (long)ldc + ct * 256 + co) =
                *(const bf16x8*)&smem[o];
        }
        __syncthreads();   // smem reused for staging next col-tile
    }
}

// ---------------- 128x128 core (heads only: fp32 out + row check) --------------
template <int ACT, bool BIAS, bool OUT_BF16, bool MCHK>
__device__ __forceinline__ void gemm_core(
    const __bf16* __restrict__ A, int lda, const __bf16* __restrict__ W,
    const float* __restrict__ bias, void* __restrict__ Cout, int ldc,
    int K, long Mstore, long blockRow, int blockCol,
    __bf16* __restrict__ smem) {
    __bf16* As = smem;
    __bf16* Ws = smem + 8192;
    const int tid  = threadIdx.x;
    const int wid  = tid >> 6;
    const int lane = tid & 63;
    const int wm = (wid >> 1) << 6;
    const int wn = (wid & 1) << 6;

    f32x4 acc[4][4];
    #pragma unroll
    for (int i = 0; i < 4; ++i)
        #pragma unroll
        for (int j = 0; j < 4; ++j) acc[i][j] = (f32x4)0.0f;

    const int srow = lane >> 3;
    const int skg  = (lane & 7) ^ srow;
    const __bf16* gA[4]; const __bf16* gW[4];
    __bf16 *lA[4], *lW[4];
    #pragma unroll
    for (int i = 0; i < 4; ++i) {
        int c = wid * 4 + i;
        gA[i] = A + (blockRow + c * 8 + srow) * (long)lda + skg * 8;
        gW[i] = W + ((long)blockCol + c * 8 + srow) * (long)K + skg * 8;
        lA[i] = As + c * 512;
        lW[i] = Ws + c * 512;
    }

    const int rA = lane & 15;
    const int q  = lane >> 4;
    const int r7 = rA & 7;

    for (int k0 = 0; k0 < K; k0 += 64) {
        #pragma unroll
        for (int i = 0; i < 4; ++i) gl_lds16(gA[i] + k0, lA[i]);
        #pragma unroll
        for (int i = 0; i < 4; ++i) gl_lds16(gW[i] + k0, lW[i]);
        __syncthreads();

        #pragma unroll
        for (int s = 0; s < 2; ++s) {
            const int slot = ((s * 4 + q) ^ r7) * 8;
            bf16x8 af[4], bf[4];
            #pragma unroll
            for (int mi = 0; mi < 4; ++mi)
                af[mi] = *(const bf16x8*)&As[(wm + mi * 16 + rA) * 64 + slot];
            #pragma unroll
            for (int ni = 0; ni < 4; ++ni)
                bf[ni] = *(const bf16x8*)&Ws[(wn + ni * 16 + rA) * 64 + slot];
            #pragma unroll
            for (int mi = 0; mi < 4; ++mi)
                #pragma unroll
                for (int ni = 0; ni < 4; ++ni)
                    acc[mi][ni] = __builtin_amdgcn_mfma_f32_16x16x32_bf16(
                        af[mi], bf[ni], acc[mi][ni], 0, 0, 0);
        }
        __syncthreads();
    }

    const int ccol = lane & 15;
    const int crow = (lane >> 4) << 2;
    #pragma unroll
    for (int mi = 0; mi < 4; ++mi) {
        #pragma unroll
        for (int ni = 0; ni < 4; ++ni) {
            long gr0 = blockRow + wm + mi * 16 + crow;
            int  gc  = blockCol + wn + ni * 16 + ccol;
            float bv = BIAS ? bias[gc] : 0.0f;
            #pragma unroll
            for (int r = 0; r < 4; ++r) {
                long gr = gr0 + r;
                if (!MCHK || gr < Mstore) {
                    float v = acc[mi][ni][r] + bv;
                    if (ACT == 1) v = (v > 0.0f) ? v : 0.1f * v;
                    else if (ACT == 2) v = fmaxf(v, 0.0f);
                    if (OUT_BF16) ((__bf16*)Cout)[gr * ldc + gc] = (__bf16)v;
                    else          ((float*)Cout)[gr * ldc + gc] = v;
                }
            }
        }
    }
}

// both heads in one 1D dispatch. K=128 (each head uses its half of p), lda=256.
__global__ __launch_bounds__(256) void gemm_heads(
    const __bf16* __restrict__ p, const __bf16* __restrict__ wm2,
    const float* __restrict__ b_m2, float* __restrict__ mu,
    const __bf16* __restrict__ wl2, const float* __restrict__ b_l2,
    float* __restrict__ lv) {
    __shared__ __bf16 smem[16384];
    int x  = blockIdx.x >> 1;
    int hd = blockIdx.x & 1;
    if (hd == 0)
        gemm_core<0, true, false, true>(p, 256, wm2, b_m2, mu, 128, 128, N_NODES,
                                        (long)x * 128, 0, smem);
    else
        gemm_core<0, true, false, true>(p + 128, 256, wl2, b_l2, lv, 128, 128, N_NODES,
                                        (long)x * 128, 0, smem);
}

extern "C" void kernel_launch(void* const* d_in, const int* in_sizes, int n_in,
                              void* d_out, int out_size, void* d_ws, size_t ws_size,
                              hipStream_t stream) {
    const float* x    = (const float*)d_in[0];
    const int*   ei   = (const int*)d_in[1];
    const float* W_s1 = (const float*)d_in[2];
    const float* b_s1 = (const float*)d_in[3];
    const float* W_s2 = (const float*)d_in[4];
    const float* b_s2 = (const float*)d_in[5];
    const float* W_s3 = (const float*)d_in[6];
    const float* b_s3 = (const float*)d_in[7];
    const float* W_s4 = (const float*)d_in[8];
    const float* b_s4 = (const float*)d_in[9];
    const float* W_m1 = (const float*)d_in[10];
    const float* b_m1 = (const float*)d_in[11];
    const float* W_m2 = (const float*)d_in[12];
    const float* b_m2 = (const float*)d_in[13];
    const float* W_l1 = (const float*)d_in[14];
    const float* b_l1 = (const float*)d_in[15];
    const float* W_l2 = (const float*)d_in[16];
    const float* b_l2 = (const float*)d_in[17];

    char* ws = (char*)d_ws;
    size_t off = 0;
    auto carve = [&](size_t bytes) -> void* {
        void* p = ws + off;
        off = (off + bytes + 255) & ~(size_t)255;
        return p;
    };
    int* cnt  = (int*)carve((size_t)N_NODES * 4);
    int* cur  = (int*)carve((size_t)N_NODES * 4);
    int* ptr  = (int*)carve((size_t)(N_NODES + 1) * 4);
    int* col  = (int*)carve((size_t)E_EDGES * 4);
    int* bsum = (int*)carve(64 * 4);
    int* boff = (int*)carve(64 * 4);
    __bf16* wbuf = (__bf16*)carve((size_t)WTOT * 2);
    __bf16* w1  = wbuf;
    __bf16* w2  = wbuf +  32768;
    __bf16* w3  = wbuf + 294912;
    __bf16* w4  = wbuf + 557056;
    __bf16* wml = wbuf + 819200;   // [W_m1 ; W_l1] rows, 256x512
    __bf16* wm2 = wbuf + 950272;
    __bf16* wl2 = wbuf + 966656;
    __bf16* xb    = (__bf16*)carve((size_t)XN * 2);
    __bf16* agg0b = (__bf16*)carve((size_t)N_PAD * 64 * 2);
    __bf16* B1    = (__bf16*)carve((size_t)N_PAD * 512 * 2);
    __bf16* B2    = (__bf16*)carve((size_t)N_PAD * 512 * 2);

    (void)hipMemsetAsync(cnt, 0, (size_t)N_NODES * 4, stream);
    (void)hipMemsetAsync(cur, 0, (size_t)N_NODES * 4, stream);

    // CSR build
    const int NB = (N_NODES + SCAN_B - 1) / SCAN_B;  // 49
    count_deg<<<E_EDGES / 256, 256, 0, stream>>>(ei, cnt);
    scan_block<<<NB, SCAN_B, 0, stream>>>(cnt, ptr, bsum, N_NODES);
    scan_bsums<<<1, 64, 0, stream>>>(bsum, boff, NB, &ptr[N_NODES]);
    scan_add<<<NB, SCAN_B, 0, stream>>>(ptr, boff, N_NODES);
    fill_csr<<<E_EDGES / 256, 256, 0, stream>>>(ei, ptr, cur, col);

    // one-shot conversions
    cvt_all<<<(XN + WTOT + 255) / 256, 256, 0, stream>>>(
        x, W_s1, W_s2, W_s3, W_s4, W_m1, W_l1, W_m2, W_l2, xb, wbuf);

    // first aggregation
    agg0_gather<<<N_PAD / 4, 256, 0, stream>>>(xb, ptr, col, agg0b);

    // shared MLP: 64->512->512->512->512, lrelu x3, final +b then relu
    gemm_wide<2, 1, true><<<MS64, 256, 0, stream>>>(agg0b, 64, w1, b_s1, B1, 512, 64);
    gemm_wide<2, 1, true><<<MS64, 256, 0, stream>>>(B1, 512, w2, b_s2, B2, 512, 512);
    gemm_wide<2, 1, true><<<MS64, 256, 0, stream>>>(B2, 512, w3, b_s3, B1, 512, 512);
    gemm_wide<2, 2, true><<<MS64, 256, 0, stream>>>(B1, 512, w4, b_s4, B2, 512, 512);

    // project h -> 256 (mu|logvar heads) BEFORE aggregation; bf16 out
    __bf16* t = B1;  // N_PAD x 256 bf16
    gemm_wide<1, 0, false><<<MS64, 256, 0, stream>>>(B2, 512, wml, nullptr, t, 256, 512);

    // second aggregation, fused bias+relu
    __bf16* p = B2;  // N x 256 bf16
    aggt_gather<<<(N_NODES + 3) / 4, 256, 0, stream>>>(t, ptr, col, b_m1, b_l1, p);

    // heads (one 1D dispatch, low bit = head)
    float* mu = (float*)d_out;
    float* lv = mu + (size_t)N_NODES * 128;
    gemm_heads<<<MT * 2, 256, 0, stream>>>(p, wm2, b_m2, mu, wl2, b_l2, lv);
}